// Round 1
// baseline (548.277 us; speedup 1.0000x reference)
//
#include <hip/hip_runtime.h>
#include <math.h>

#define PI_F 3.14159265358979323846f

// map from output slot k (0..24, the reference's radius/angle-sorted order)
// to canonical unique-bin id (0..16) exploiting mag[u,v] == mag[-u,-v].
// canonical bins: 0:(0,0) 1:(0,1) 2:(0,2) 3:(0,3) 4:(1,0) 5:(1,1) 6:(1,-1)
// 7:(1,2) 8:(1,-2) 9:(1,3) 10:(2,0) 11:(2,1) 12:(2,-1) 13:(2,2) 14:(2,3)
// 15:(3,0) 16:(3,1)
__constant__ int d_map25[25] = {5,4,0,1,7,11,10,6,1,4,6,2,13,12,5,8,9,16,15,8,2,10,12,3,14};

__global__ void __launch_bounds__(192)
fft_lowfreq_kernel(const float* __restrict__ x, float* __restrict__ out)
{
    __shared__ float lds_mag[3 * 17];
    const int tid  = threadIdx.x;
    const int c    = tid >> 6;    // wave index == channel
    const int lane = tid & 63;
    const int b    = blockIdx.x;

    const float4* img4 = (const float4*)(x + (((size_t)b * 3 + c) << 14)); // 128*128 floats

    // lane owns columns x0..x0+3; rows y = 2*i + yhi for i = 0..63
    const int x0  = (4 * lane) & 127;
    const int yhi = lane >> 5;

    // column phases P_v[j] = e^{-2*pi*i * v * (x0+j) / 128}, v = 1..3
    float Pr[3][4], Pi[3][4];
#pragma unroll
    for (int v = 1; v <= 3; ++v) {
#pragma unroll
        for (int j = 0; j < 4; ++j) {
            float s, cc;
            sincosf(-2.0f * PI_F * (float)(v * (x0 + j)) * (1.0f / 128.0f), &s, &cc);
            Pr[v - 1][j] = cc; Pi[v - 1][j] = s;
        }
    }

    // row twiddles w_u = e^{-2*pi*i*u*y/128} at y = yhi; rotation step for y += 2
    float wr[3], wi[3], er[3], ei[3];
#pragma unroll
    for (int u = 1; u <= 3; ++u) {
        float s, cc;
        sincosf(-2.0f * PI_F * (float)(u * yhi) * (1.0f / 128.0f), &s, &cc);
        wr[u - 1] = cc; wi[u - 1] = s;
        sincosf(-2.0f * PI_F * (float)(2 * u) * (1.0f / 128.0f), &s, &cc);
        er[u - 1] = cc; ei[u - 1] = s;
    }

    // B_u[j] = sum_y x[y, x0+j] * w_u(y)   (u = 0..3; u=0 is real)
    float B0[4]  = {0, 0, 0, 0};
    float B1r[4] = {0, 0, 0, 0}, B1i[4] = {0, 0, 0, 0};
    float B2r[4] = {0, 0, 0, 0}, B2i[4] = {0, 0, 0, 0};
    float B3r[4] = {0, 0, 0, 0}, B3i[4] = {0, 0, 0, 0};

#pragma unroll 4
    for (int i = 0; i < 64; ++i) {
        float4 v4 = img4[i * 64 + lane];   // contiguous 1KB per wave instruction
        float vals[4] = {v4.x, v4.y, v4.z, v4.w};
#pragma unroll
        for (int j = 0; j < 4; ++j) {
            float val = vals[j];
            B0[j]  += val;
            B1r[j] = fmaf(val, wr[0], B1r[j]);
            B1i[j] = fmaf(val, wi[0], B1i[j]);
            B2r[j] = fmaf(val, wr[1], B2r[j]);
            B2i[j] = fmaf(val, wi[1], B2i[j]);
            B3r[j] = fmaf(val, wr[2], B3r[j]);
            B3i[j] = fmaf(val, wi[2], B3i[j]);
        }
#pragma unroll
        for (int u = 0; u < 3; ++u) {      // rotate row twiddles by e^{-2*pi*i*2u/128}
            float nr = wr[u] * er[u] - wi[u] * ei[u];
            float ni = wr[u] * ei[u] + wi[u] * er[u];
            wr[u] = nr; wi[u] = ni;
        }
    }

    // per-lane partial X for the 17 canonical bins: X[u,v] += B_u[j] * P_v[x0+j]
    float XR[17], XI[17];
    XR[0] = B0[0] + B0[1] + B0[2] + B0[3];  XI[0] = 0.0f;
#pragma unroll
    for (int v = 1; v <= 3; ++v) {
        float xr = 0.f, xi = 0.f;
#pragma unroll
        for (int j = 0; j < 4; ++j) {
            xr = fmaf(B0[j], Pr[v - 1][j], xr);
            xi = fmaf(B0[j], Pi[v - 1][j], xi);
        }
        XR[v] = xr; XI[v] = xi;
    }

#define CDOT(BR, BI, V, SGN, K) do {                         \
    float xr = 0.f, xi = 0.f;                                \
    _Pragma("unroll")                                        \
    for (int j = 0; j < 4; ++j) {                            \
        float pr = Pr[(V) - 1][j], pi = (SGN) * Pi[(V) - 1][j]; \
        xr += BR[j] * pr - BI[j] * pi;                       \
        xi += BR[j] * pi + BI[j] * pr;                       \
    }                                                        \
    XR[K] = xr; XI[K] = xi; } while (0)

    XR[4]  = B1r[0] + B1r[1] + B1r[2] + B1r[3];  XI[4]  = B1i[0] + B1i[1] + B1i[2] + B1i[3];
    CDOT(B1r, B1i, 1,  1.0f, 5);
    CDOT(B1r, B1i, 1, -1.0f, 6);
    CDOT(B1r, B1i, 2,  1.0f, 7);
    CDOT(B1r, B1i, 2, -1.0f, 8);
    CDOT(B1r, B1i, 3,  1.0f, 9);
    XR[10] = B2r[0] + B2r[1] + B2r[2] + B2r[3];  XI[10] = B2i[0] + B2i[1] + B2i[2] + B2i[3];
    CDOT(B2r, B2i, 1,  1.0f, 11);
    CDOT(B2r, B2i, 1, -1.0f, 12);
    CDOT(B2r, B2i, 2,  1.0f, 13);
    CDOT(B2r, B2i, 3,  1.0f, 14);
    XR[15] = B3r[0] + B3r[1] + B3r[2] + B3r[3];  XI[15] = B3i[0] + B3i[1] + B3i[2] + B3i[3];
    CDOT(B3r, B3i, 1,  1.0f, 16);
#undef CDOT

    // full-wave xor butterfly: every lane ends with the wave-wide sums
#pragma unroll
    for (int k = 0; k < 17; ++k) {
#pragma unroll
        for (int off = 32; off > 0; off >>= 1) {
            XR[k] += __shfl_xor(XR[k], off, 64);
            XI[k] += __shfl_xor(XI[k], off, 64);
        }
    }

    if (lane == 0) {
#pragma unroll
        for (int k = 0; k < 17; ++k) {
            float m = sqrtf(XR[k] * XR[k] + XI[k] * XI[k]);
            lds_mag[c * 17 + k] = log1pf(m + 1e-12f);
        }
    }
    __syncthreads();

    if (tid < 25) {
        const int id = d_map25[tid];
        float s = lds_mag[id] + lds_mag[17 + id] + lds_mag[34 + id];
        out[(size_t)b * 25 + tid] = s * (1.0f / 3.0f);
    }
}

extern "C" void kernel_launch(void* const* d_in, const int* in_sizes, int n_in,
                              void* d_out, int out_size, void* d_ws, size_t ws_size,
                              hipStream_t stream)
{
    const float* x = (const float*)d_in[0];
    float* out = (float*)d_out;
    const int B = in_sizes[0] / (3 * 128 * 128);   // 2048
    fft_lowfreq_kernel<<<B, 192, 0, stream>>>(x, out);
}

// Round 2
// 527.593 us; speedup vs baseline: 1.0392x; 1.0392x over previous
//
#include <hip/hip_runtime.h>
#include <math.h>

#define PI_F 3.14159265358979323846f

// map from output slot k (0..24, the reference's radius/angle-sorted order)
// to canonical unique-bin id (0..16) exploiting mag[u,v] == mag[-u,-v].
// canonical bins: 0:(0,0) 1:(0,1) 2:(0,2) 3:(0,3) 4:(1,0) 5:(1,1) 6:(1,-1)
// 7:(1,2) 8:(1,-2) 9:(1,3) 10:(2,0) 11:(2,1) 12:(2,-1) 13:(2,2) 14:(2,3)
// 15:(3,0) 16:(3,1)
__constant__ int d_map25[25] = {5,4,0,1,7,11,10,6,1,4,6,2,13,12,5,8,9,16,15,8,2,10,12,3,14};

__global__ void __launch_bounds__(192)
fft_lowfreq_kernel(const float* __restrict__ x, float* __restrict__ out)
{
    __shared__ float lds_mag[3 * 17];
    const int tid  = threadIdx.x;
    const int c    = tid >> 6;    // wave index == channel
    const int lane = tid & 63;
    const int b    = blockIdx.x;

    const float4* img4 = (const float4*)(x + (((size_t)b * 3 + c) << 14)); // 128*128 floats

    // lane owns columns x0..x0+3; rows y = 2*i + yhi (i=0..31) and y+64
    const int x0   = (4 * lane) & 127;
    const int yhi  = lane >> 5;
    const int col4 = lane & 31;          // float4 column-group index within a row

    // row twiddles w_u = e^{-2*pi*i*u*y/128} at y = yhi; rotation step for y += 2
    float wr[3], wi[3], er[3], ei[3];
#pragma unroll
    for (int u = 1; u <= 3; ++u) {
        float s, cc;
        sincosf(-2.0f * PI_F * (float)(u * yhi) * (1.0f / 128.0f), &s, &cc);
        wr[u - 1] = cc; wi[u - 1] = s;
        sincosf(-2.0f * PI_F * (float)(2 * u) * (1.0f / 128.0f), &s, &cc);
        er[u - 1] = cc; ei[u - 1] = s;
    }

    // y-folded accumulators over the lane's 4 columns:
    //   s = v(y) + v(y+64), d = v(y) - v(y+64)
    //   B0 += s; B1 += d*w1; B2 += s*w2; B3 += d*w3   (w_u = w_u(y))
    float B0[4]  = {0, 0, 0, 0};
    float B1r[4] = {0, 0, 0, 0}, B1i[4] = {0, 0, 0, 0};
    float B2r[4] = {0, 0, 0, 0}, B2i[4] = {0, 0, 0, 0};
    float B3r[4] = {0, 0, 0, 0}, B3i[4] = {0, 0, 0, 0};

#pragma unroll 4
    for (int i = 0; i < 32; ++i) {
        const int y = 2 * i + yhi;
        float4 va = img4[y * 32 + col4];          // row y      (512B/half-wave, coalesced)
        float4 vb = img4[(y + 64) * 32 + col4];   // row y+64   (independent load: MLP x2)
        float sa[4] = {va.x + vb.x, va.y + vb.y, va.z + vb.z, va.w + vb.w};
        float da[4] = {va.x - vb.x, va.y - vb.y, va.z - vb.z, va.w - vb.w};
#pragma unroll
        for (int j = 0; j < 4; ++j) {
            B0[j]  += sa[j];
            B1r[j] = fmaf(da[j], wr[0], B1r[j]);
            B1i[j] = fmaf(da[j], wi[0], B1i[j]);
            B2r[j] = fmaf(sa[j], wr[1], B2r[j]);
            B2i[j] = fmaf(sa[j], wi[1], B2i[j]);
            B3r[j] = fmaf(da[j], wr[2], B3r[j]);
            B3i[j] = fmaf(da[j], wi[2], B3i[j]);
        }
#pragma unroll
        for (int u = 0; u < 3; ++u) {      // rotate row twiddles by e^{-2*pi*i*2u/128}
            float nr = wr[u] * er[u] - wi[u] * ei[u];
            float ni = wr[u] * ei[u] + wi[u] * er[u];
            wr[u] = nr; wi[u] = ni;
        }
    }

    // column phases P_v[j] = e^{-2*pi*i * v * (x0+j) / 128}, v = 1..3
    // (computed AFTER the hot loop to keep inner-loop register pressure low)
    float Pr[3][4], Pi[3][4];
#pragma unroll
    for (int v = 1; v <= 3; ++v) {
#pragma unroll
        for (int j = 0; j < 4; ++j) {
            float s, cc;
            sincosf(-2.0f * PI_F * (float)(v * (x0 + j)) * (1.0f / 128.0f), &s, &cc);
            Pr[v - 1][j] = cc; Pi[v - 1][j] = s;
        }
    }

    // per-lane partial X for the 17 canonical bins: X[u,v] += B_u[j] * P_v[x0+j]
    float XR[17], XI[17];
    XR[0] = B0[0] + B0[1] + B0[2] + B0[3];  XI[0] = 0.0f;
#pragma unroll
    for (int v = 1; v <= 3; ++v) {
        float xr = 0.f, xi = 0.f;
#pragma unroll
        for (int j = 0; j < 4; ++j) {
            xr = fmaf(B0[j], Pr[v - 1][j], xr);
            xi = fmaf(B0[j], Pi[v - 1][j], xi);
        }
        XR[v] = xr; XI[v] = xi;
    }

#define CDOT(BR, BI, V, SGN, K) do {                         \
    float xr = 0.f, xi = 0.f;                                \
    _Pragma("unroll")                                        \
    for (int j = 0; j < 4; ++j) {                            \
        float pr = Pr[(V) - 1][j], pi = (SGN) * Pi[(V) - 1][j]; \
        xr += BR[j] * pr - BI[j] * pi;                       \
        xi += BR[j] * pi + BI[j] * pr;                       \
    }                                                        \
    XR[K] = xr; XI[K] = xi; } while (0)

    XR[4]  = B1r[0] + B1r[1] + B1r[2] + B1r[3];  XI[4]  = B1i[0] + B1i[1] + B1i[2] + B1i[3];
    CDOT(B1r, B1i, 1,  1.0f, 5);
    CDOT(B1r, B1i, 1, -1.0f, 6);
    CDOT(B1r, B1i, 2,  1.0f, 7);
    CDOT(B1r, B1i, 2, -1.0f, 8);
    CDOT(B1r, B1i, 3,  1.0f, 9);
    XR[10] = B2r[0] + B2r[1] + B2r[2] + B2r[3];  XI[10] = B2i[0] + B2i[1] + B2i[2] + B2i[3];
    CDOT(B2r, B2i, 1,  1.0f, 11);
    CDOT(B2r, B2i, 1, -1.0f, 12);
    CDOT(B2r, B2i, 2,  1.0f, 13);
    CDOT(B2r, B2i, 3,  1.0f, 14);
    XR[15] = B3r[0] + B3r[1] + B3r[2] + B3r[3];  XI[15] = B3i[0] + B3i[1] + B3i[2] + B3i[3];
    CDOT(B3r, B3i, 1,  1.0f, 16);
#undef CDOT

    // full-wave xor butterfly: every lane ends with the wave-wide sums
#pragma unroll
    for (int k = 0; k < 17; ++k) {
#pragma unroll
        for (int off = 32; off > 0; off >>= 1) {
            XR[k] += __shfl_xor(XR[k], off, 64);
            XI[k] += __shfl_xor(XI[k], off, 64);
        }
    }

    if (lane == 0) {
#pragma unroll
        for (int k = 0; k < 17; ++k) {
            float m = sqrtf(XR[k] * XR[k] + XI[k] * XI[k]);
            lds_mag[c * 17 + k] = log1pf(m + 1e-12f);
        }
    }
    __syncthreads();

    if (tid < 25) {
        const int id = d_map25[tid];
        float s = lds_mag[id] + lds_mag[17 + id] + lds_mag[34 + id];
        out[(size_t)b * 25 + tid] = s * (1.0f / 3.0f);
    }
}

extern "C" void kernel_launch(void* const* d_in, const int* in_sizes, int n_in,
                              void* d_out, int out_size, void* d_ws, size_t ws_size,
                              hipStream_t stream)
{
    const float* x = (const float*)d_in[0];
    float* out = (float*)d_out;
    const int B = in_sizes[0] / (3 * 128 * 128);   // 2048
    fft_lowfreq_kernel<<<B, 192, 0, stream>>>(x, out);
}

// Round 3
// 519.692 us; speedup vs baseline: 1.0550x; 1.0152x over previous
//
#include <hip/hip_runtime.h>
#include <math.h>

#define PI_F 3.14159265358979323846f

// map from output slot k (0..24, the reference's radius/angle-sorted order)
// to canonical unique-bin id (0..16) exploiting mag[u,v] == mag[-u,-v].
// canonical bins: 0:(0,0) 1:(0,1) 2:(0,2) 3:(0,3) 4:(1,0) 5:(1,1) 6:(1,-1)
// 7:(1,2) 8:(1,-2) 9:(1,3) 10:(2,0) 11:(2,1) 12:(2,-1) 13:(2,2) 14:(2,3)
// 15:(3,0) 16:(3,1)
__constant__ int d_map25[25] = {5,4,0,1,7,11,10,6,1,4,6,2,13,12,5,8,9,16,15,8,2,10,12,3,14};

// 6 waves/block: wave w handles channel c=w>>1, row-subset sub=w&1.
// Each wave reads 32 rows (16 folded pairs) => half the serial chain of R2.
__global__ void __launch_bounds__(384)
fft_lowfreq_kernel(const float* __restrict__ x, float* __restrict__ out)
{
    __shared__ float lds_X[6][34];     // per-wave partial XR[0..16], XI[0..16]
    __shared__ float lds_mag[3 * 17];  // per-channel log1p magnitudes
    const int tid  = threadIdx.x;
    const int w    = tid >> 6;
    const int c    = w >> 1;           // channel
    const int sub  = w & 1;            // row-subset within channel
    const int lane = tid & 63;
    const int b    = blockIdx.x;

    const float4* img4 = (const float4*)(x + (((size_t)b * 3 + c) << 14)); // 128*128 floats

    const int yhi  = lane >> 5;
    const int col4 = lane & 31;          // float4 column-group index within a row
    const int x0   = 4 * col4;           // first of the lane's 4 columns
    const int y0   = 2 * sub + yhi;      // starting row; stride 4 over i

    // row twiddles w_u = e^{-2*pi*i*u*y/128} at y=y0; rotation step for y += 4
    float wr[3], wi[3], er[3], ei[3];
#pragma unroll
    for (int u = 1; u <= 3; ++u) {
        float s, cc;
        sincosf(-2.0f * PI_F * (float)(u * y0) * (1.0f / 128.0f), &s, &cc);
        wr[u - 1] = cc; wi[u - 1] = s;
        sincosf(-2.0f * PI_F * (float)(4 * u) * (1.0f / 128.0f), &s, &cc);
        er[u - 1] = cc; ei[u - 1] = s;
    }

    // y-folded accumulators over the lane's 4 columns:
    //   s = v(y) + v(y+64), d = v(y) - v(y+64)
    //   B0 += s; B1 += d*w1; B2 += s*w2; B3 += d*w3   (w_u = w_u(y))
    float B0[4]  = {0, 0, 0, 0};
    float B1r[4] = {0, 0, 0, 0}, B1i[4] = {0, 0, 0, 0};
    float B2r[4] = {0, 0, 0, 0}, B2i[4] = {0, 0, 0, 0};
    float B3r[4] = {0, 0, 0, 0}, B3i[4] = {0, 0, 0, 0};

#pragma unroll 4
    for (int i = 0; i < 16; ++i) {
        const int y = 4 * i + y0;
        float4 va = img4[y * 32 + col4];          // row y      (coalesced 512B/half-wave)
        float4 vb = img4[(y + 64) * 32 + col4];   // row y+64   (independent load: MLP x2)
        float sa[4] = {va.x + vb.x, va.y + vb.y, va.z + vb.z, va.w + vb.w};
        float da[4] = {va.x - vb.x, va.y - vb.y, va.z - vb.z, va.w - vb.w};
#pragma unroll
        for (int j = 0; j < 4; ++j) {
            B0[j]  += sa[j];
            B1r[j] = fmaf(da[j], wr[0], B1r[j]);
            B1i[j] = fmaf(da[j], wi[0], B1i[j]);
            B2r[j] = fmaf(sa[j], wr[1], B2r[j]);
            B2i[j] = fmaf(sa[j], wi[1], B2i[j]);
            B3r[j] = fmaf(da[j], wr[2], B3r[j]);
            B3i[j] = fmaf(da[j], wi[2], B3i[j]);
        }
#pragma unroll
        for (int u = 0; u < 3; ++u) {      // rotate row twiddles by e^{-2*pi*i*4u/128}
            float nr = wr[u] * er[u] - wi[u] * ei[u];
            float ni = wr[u] * ei[u] + wi[u] * er[u];
            wr[u] = nr; wi[u] = ni;
        }
    }

    // column phases P_v[j] = e^{-2*pi*i * v * (x0+j) / 128}, v = 1..3
    // (computed AFTER the hot loop to keep inner-loop register pressure low)
    float Pr[3][4], Pi[3][4];
#pragma unroll
    for (int v = 1; v <= 3; ++v) {
#pragma unroll
        for (int j = 0; j < 4; ++j) {
            float s, cc;
            sincosf(-2.0f * PI_F * (float)(v * (x0 + j)) * (1.0f / 128.0f), &s, &cc);
            Pr[v - 1][j] = cc; Pi[v - 1][j] = s;
        }
    }

    // per-lane partial X for the 17 canonical bins: X[u,v] += B_u[j] * P_v[x0+j]
    float XR[17], XI[17];
    XR[0] = B0[0] + B0[1] + B0[2] + B0[3];  XI[0] = 0.0f;
#pragma unroll
    for (int v = 1; v <= 3; ++v) {
        float xr = 0.f, xi = 0.f;
#pragma unroll
        for (int j = 0; j < 4; ++j) {
            xr = fmaf(B0[j], Pr[v - 1][j], xr);
            xi = fmaf(B0[j], Pi[v - 1][j], xi);
        }
        XR[v] = xr; XI[v] = xi;
    }

#define CDOT(BR, BI, V, SGN, K) do {                         \
    float xr = 0.f, xi = 0.f;                                \
    _Pragma("unroll")                                        \
    for (int j = 0; j < 4; ++j) {                            \
        float pr = Pr[(V) - 1][j], pi = (SGN) * Pi[(V) - 1][j]; \
        xr += BR[j] * pr - BI[j] * pi;                       \
        xi += BR[j] * pi + BI[j] * pr;                       \
    }                                                        \
    XR[K] = xr; XI[K] = xi; } while (0)

    XR[4]  = B1r[0] + B1r[1] + B1r[2] + B1r[3];  XI[4]  = B1i[0] + B1i[1] + B1i[2] + B1i[3];
    CDOT(B1r, B1i, 1,  1.0f, 5);
    CDOT(B1r, B1i, 1, -1.0f, 6);
    CDOT(B1r, B1i, 2,  1.0f, 7);
    CDOT(B1r, B1i, 2, -1.0f, 8);
    CDOT(B1r, B1i, 3,  1.0f, 9);
    XR[10] = B2r[0] + B2r[1] + B2r[2] + B2r[3];  XI[10] = B2i[0] + B2i[1] + B2i[2] + B2i[3];
    CDOT(B2r, B2i, 1,  1.0f, 11);
    CDOT(B2r, B2i, 1, -1.0f, 12);
    CDOT(B2r, B2i, 2,  1.0f, 13);
    CDOT(B2r, B2i, 3,  1.0f, 14);
    XR[15] = B3r[0] + B3r[1] + B3r[2] + B3r[3];  XI[15] = B3i[0] + B3i[1] + B3i[2] + B3i[3];
    CDOT(B3r, B3i, 1,  1.0f, 16);
#undef CDOT

    // full-wave xor butterfly: every lane ends with the wave-wide sums
#pragma unroll
    for (int k = 0; k < 17; ++k) {
#pragma unroll
        for (int off = 32; off > 0; off >>= 1) {
            XR[k] += __shfl_xor(XR[k], off, 64);
            XI[k] += __shfl_xor(XI[k], off, 64);
        }
    }

    if (lane == 0) {
#pragma unroll
        for (int k = 0; k < 17; ++k) {
            lds_X[w][k]      = XR[k];
            lds_X[w][k + 17] = XI[k];
        }
    }
    __syncthreads();

    // combine the two row-subset waves per channel, then magnitude + log1p
    if (tid < 51) {
        const int cc = tid / 17;
        const int k  = tid - 17 * cc;
        float xr = lds_X[2 * cc][k]      + lds_X[2 * cc + 1][k];
        float xi = lds_X[2 * cc][k + 17] + lds_X[2 * cc + 1][k + 17];
        float m = sqrtf(xr * xr + xi * xi);
        lds_mag[cc * 17 + k] = log1pf(m + 1e-12f);
    }
    __syncthreads();

    if (tid < 25) {
        const int id = d_map25[tid];
        float s = lds_mag[id] + lds_mag[17 + id] + lds_mag[34 + id];
        out[(size_t)b * 25 + tid] = s * (1.0f / 3.0f);
    }
}

extern "C" void kernel_launch(void* const* d_in, const int* in_sizes, int n_in,
                              void* d_out, int out_size, void* d_ws, size_t ws_size,
                              hipStream_t stream)
{
    const float* x = (const float*)d_in[0];
    float* out = (float*)d_out;
    const int B = in_sizes[0] / (3 * 128 * 128);   // 2048
    fft_lowfreq_kernel<<<B, 384, 0, stream>>>(x, out);
}